// Round 5
// baseline (569.408 us; speedup 1.0000x reference)
//
#include <hip/hip_runtime.h>
#include <hip/hip_bf16.h>
#include <stdint.h>

#define DEV __device__ __forceinline__
#define WAITV(n) asm volatile("s_waitcnt vmcnt(" #n ")" ::: "memory")

typedef __attribute__((ext_vector_type(4))) float f32x4;
typedef __attribute__((ext_vector_type(8))) short bf16x8;
typedef unsigned short u16;

constexpr int Bb = 4, Tt = 2048, Ccn = 2048, NHn = 16, HDn = 128;
constexpr int MM = Bb * Tt;          // 8192
constexpr int NQKV = 3 * Ccn;        // 6144
constexpr float QSCALE = 0.08838834764831845f;  // 1/sqrt(128)

DEV u16 f2bf(float f) {
  __hip_bfloat16 h = __float2bfloat16(f);
  return *reinterpret_cast<u16*>(&h);
}

DEV void gl_lds16(const void* g, void* l) {
  __builtin_amdgcn_global_load_lds(
      (const __attribute__((address_space(1))) void*)g,
      (__attribute__((address_space(3))) void*)l, 16, 0, 0);
}

// ---------------- prep kernels ----------------

__global__ void k_rope_table(float* __restrict__ ct, float* __restrict__ st) {
  int idx = blockIdx.x * blockDim.x + threadIdx.x;
  if (idx >= Tt * 64) return;
  int t = idx >> 6, j = idx & 63;
  float invf = expf(-(float)j * 0.14391157f);  // ln(10000)/64
  float a = (float)t * invf;
  ct[idx] = cosf(a);
  st[idx] = sinf(a);
}

__global__ void k_cvt(const float* __restrict__ in, u16* __restrict__ out, int n) {
  int i = blockIdx.x * blockDim.x + threadIdx.x;
  int stride = gridDim.x * blockDim.x;
  int n4 = n >> 2;
  for (int idx = i; idx < n4; idx += stride) {
    float4 v = ((const float4*)in)[idx];
    ushort4 o;
    o.x = f2bf(v.x); o.y = f2bf(v.y); o.z = f2bf(v.z); o.w = f2bf(v.w);
    ((ushort4*)out)[idx] = o;
  }
}

// in: fp32 [R][NC]  ->  out: bf16 [NC][R]
__global__ void k_transpose_cvt(const float* __restrict__ in, u16* __restrict__ out,
                                int R, int NC) {
  __shared__ u16 tile[64][72];
  int tr = blockIdx.y * 64, tc = blockIdx.x * 64;
  int r = threadIdx.x >> 2, c = (threadIdx.x & 3) * 16;
  const float* src = in + (size_t)(tr + r) * NC + tc + c;
#pragma unroll
  for (int i = 0; i < 16; i++) tile[r][c + i] = f2bf(src[i]);
  __syncthreads();
  u16* dst = out + (size_t)(tc + r) * R + tr + c;
#pragma unroll
  for (int i = 0; i < 16; i++) dst[i] = tile[c + i][r];
}

// v [BH][T][D] -> vt [BH][D][T]
__global__ void k_vtrans(const u16* __restrict__ v, u16* __restrict__ vt) {
  __shared__ u16 tile[64][72];
  int bh = blockIdx.z;
  int t0 = blockIdx.x * 64, d0 = blockIdx.y * 64;
  int r = threadIdx.x >> 2, c = (threadIdx.x & 3) * 16;
  const u16* src = v + ((size_t)bh * Tt + t0) * HDn + d0;
#pragma unroll
  for (int i = 0; i < 16; i++) tile[r][c + i] = src[(size_t)r * HDn + c + i];
  __syncthreads();
  u16* dst = vt + ((size_t)bh * HDn + d0) * Tt + t0;
#pragma unroll
  for (int i = 0; i < 16; i++) dst[(size_t)r * Tt + c + i] = tile[c + i][r];
}

// ---------------- 256x256 8-phase GEMM (A [M][K] x Bt [N][K], bf16) ------
// 8 waves (2Mx4N), BK=64, 2 K-tiles/iteration, 8 phases, counted vmcnt.
// Block->tile mapping: COLUMN-PATCH per XCD. Blocks with bid%8==x land on
// XCD x (dispatch round-robin); within an XCD, j=bid/8 walks by-major so
// the 32 concurrently-resident blocks of an XCD share ONE B-panel
// (256xK bf16 = 0.5-1MB, L2-resident) and stream distinct A-panels from
// L3. R4's row-major patch gave each XCD the whole 24MB B matrix ->
// staging-supply-bound at 31% MfmaUtil.

template <int MODE>
__global__ __launch_bounds__(512, 2) void k_gemm256(
    const u16* __restrict__ A, const u16* __restrict__ Bt,
    int Ndim, int Kdim, int NBX,
    const float* __restrict__ bias,
    u16* __restrict__ q_r, u16* __restrict__ k_r, u16* __restrict__ v_r,
    const float* __restrict__ ctab, const float* __restrict__ stab,
    float* __restrict__ outp) {
  __shared__ u16 As[2][2][8192];   // [buf][half][128*64]
  __shared__ u16 Bs[2][2][8192];
  const int tid = threadIdx.x;
  const int w = tid >> 6, lane = tid & 63;
  const int l16 = lane & 15, l4 = lane >> 4;
  const int wr = w >> 2, wc = w & 3;
  const int bid = blockIdx.x;
  const int NBY = gridDim.x / NBX;          // 32 here
  const int BXP = NBX >> 3;                 // B-panels per XCD (3 or 1)
  const int xcd = bid & 7, jj_ = bid >> 3;
  const int by = jj_ % NBY, bx = xcd * BXP + jj_ / NBY;
  const int m0 = by * 256, n0 = bx * 256;
  const int NT = Kdim >> 6;
  const int NIT = NT >> 1;

  auto stA = [&](int buf, int half, int kt) {
#pragma unroll
    for (int i = 0; i < 2; i++) {
      int op = i * 8192 + tid * 16;
      int ol = op ^ (((op >> 7) & 7) << 4);
      int row = ol >> 7, colb = ol & 127;
      gl_lds16((const char*)(A + (size_t)(m0 + half * 128 + row) * Kdim + kt * 64) + colb,
               (char*)&As[buf][half][0] + op);
    }
  };
  auto stB = [&](int buf, int half, int kt) {
#pragma unroll
    for (int i = 0; i < 2; i++) {
      int op = i * 8192 + tid * 16;
      int ol = op ^ (((op >> 7) & 7) << 4);
      int row = ol >> 7, colb = ol & 127;
      gl_lds16((const char*)(Bt + (size_t)(n0 + half * 128 + row) * Kdim + kt * 64) + colb,
               (char*)&Bs[buf][half][0] + op);
    }
  };
  auto rdA = [&](int buf, int mi, int ks) -> bf16x8 {
    int row = mi * 16 + l16;
    int kb = ks * 64 + l4 * 16;
    return *(const bf16x8*)((const char*)&As[buf][wr][0] + row * 128 + (kb ^ ((row & 7) << 4)));
  };
  auto rdB = [&](int buf, int nj, int ks) -> bf16x8 {
    int row = (wc & 1) * 64 + nj * 16 + l16;
    int kb = ks * 64 + l4 * 16;
    return *(const bf16x8*)((const char*)&Bs[buf][wc >> 1][0] + row * 128 + (kb ^ ((row & 7) << 4)));
  };

  f32x4 acc[8][4];
  const f32x4 zf = {0.f, 0.f, 0.f, 0.f};
#pragma unroll
  for (int i = 0; i < 8; i++)
#pragma unroll
    for (int j = 0; j < 4; j++) acc[i][j] = zf;

  // prologue: tile0 (A,B) + tile1 (B); tile1 A staged in iter0 ph0/ph1
  stA(0, 0, 0); stA(0, 1, 0); stB(0, 0, 0); stB(0, 1, 0);
  stB(1, 0, 1); stB(1, 1, 1);
  WAITV(4);                       // tile0 landed; tile1-B in flight
  __builtin_amdgcn_s_barrier();

  bf16x8 bfrag[4][2];
  for (int I = 0; I < NIT; ++I) {
    const int t1 = 2 * I + 1, t2 = 2 * I + 2, t3 = 2 * I + 3;
#pragma unroll
    for (int buf = 0; buf < 2; ++buf) {
#pragma unroll
      for (int ph = 0; ph < 4; ++ph) {
        const int gp = buf * 4 + ph;
        // ---- ds-reads for this phase's quadrant ----
        if (ph == 0) {
#pragma unroll
          for (int nj = 0; nj < 4; nj++)
#pragma unroll
            for (int ks = 0; ks < 2; ks++) bfrag[nj][ks] = rdB(buf, nj, ks);
        }
        bf16x8 af[2][2];
#pragma unroll
        for (int dm = 0; dm < 2; dm++)
#pragma unroll
          for (int ks = 0; ks < 2; ks++) af[dm][ks] = rdA(buf, ph * 2 + dm, ks);
        // ---- stage one half-tile ----
        if (gp == 0)      stA(1, 0, t1);
        else if (gp == 1) stA(1, 1, t1);
        else if (gp == 2) { if (t2 < NT) stB(0, 0, t2); }
        else if (gp == 3) {
          if (t2 < NT) stB(0, 1, t2);
          if (I < NIT - 1) { WAITV(4); } else { WAITV(0); }
        }
        else if (gp == 4) { if (t2 < NT) stA(0, 0, t2); }
        else if (gp == 5) { if (t2 < NT) stA(0, 1, t2); }
        else if (gp == 6) { if (t3 < NT) stB(1, 0, t3); }
        else if (gp == 7) { if (t3 < NT) { stB(1, 1, t3); WAITV(4); } }
        __builtin_amdgcn_s_barrier();
        // ---- 16 MFMA, ks-outer: 8 independent between dependent reuses ----
        __builtin_amdgcn_s_setprio(1);
#pragma unroll
        for (int ks = 0; ks < 2; ks++)
#pragma unroll
          for (int dm = 0; dm < 2; dm++)
#pragma unroll
            for (int nj = 0; nj < 4; nj++)
              acc[ph * 2 + dm][nj] = __builtin_amdgcn_mfma_f32_16x16x32_bf16(
                  af[dm][ks], bfrag[nj][ks], acc[ph * 2 + dm][nj], 0, 0, 0);
        __builtin_amdgcn_s_setprio(0);
        __builtin_amdgcn_s_barrier();
      }
    }
  }

  if constexpr (MODE == 1) {
#pragma unroll
    for (int mi = 0; mi < 8; mi++) {
      const int mrow = m0 + wr * 128 + mi * 16 + l4 * 4;
#pragma unroll
      for (int nj = 0; nj < 4; nj++) {
        const int col = n0 + wc * 64 + nj * 16 + l16;
        const float bi = bias[col];
#pragma unroll
        for (int jj = 0; jj < 4; jj++)
          outp[(size_t)(mrow + jj) * Ndim + col] = acc[mi][nj][jj] + bi;
      }
    }
  } else {
#pragma unroll
    for (int mi = 0; mi < 8; mi++) {
      const int mrow = m0 + wr * 128 + mi * 16 + l4 * 4;
#pragma unroll
      for (int nj = 0; nj < 4; nj++) {
        const int n = n0 + wc * 64 + nj * 16 + l16;
        const float bi = bias[n];
        const int part = n >> 11;          // 0=q 1=k 2=v
        const int hcol = n & 2047;
        const int h = hcol >> 7, d = hcol & 127;
        const int dm = d & 63;
#pragma unroll
        for (int jj = 0; jj < 4; jj++) {
          const int m = mrow + jj;
          const int b = m >> 11, t = m & 2047;
          float val = acc[mi][nj][jj] + bi;
          size_t didx = (((size_t)b * NHn + h) * Tt + t) * HDn + d;
          if (part == 2) {
            v_r[didx] = f2bf(val);
          } else {
            float partner = __shfl_xor(val, 1);
            float rh = (d & 1) ? partner : -partner;
            float cs = ctab[t * 64 + dm], sn = stab[t * 64 + dm];
            float o = val * cs + rh * sn;
            if (part == 0) q_r[didx] = f2bf(o * QSCALE);
            else           k_r[didx] = f2bf(o);
          }
        }
      }
    }
  }
}

// ---------------- flash attention (causal), overlapped LDS staging -------
// grid: 512 blocks (8 q-tile-pairs x 64 bh); block: 256 (4 waves x 32 q-rows).
// Per tile j: issue V(j)-stage + K(j+1)-stage at loop top (fly under
// QK^T+softmax); vmcnt(4)+raw barrier before PV (V landed, K(j+1) in
// flight); __syncthreads at tile end = vmcnt(0) for K(j+1).
__global__ __launch_bounds__(256, 2) void k_attn(
    const u16* __restrict__ q_r, const u16* __restrict__ k_r,
    const u16* __restrict__ vt, u16* __restrict__ y) {
  __shared__ u16 Ks[2][64 * 128];  // [buf][key][d], swizzled, 32KB
  __shared__ u16 Vs[128 * 64];     // V^T [d][key], swizzled, 16KB
  __shared__ u16 Ps[4][32 * 72];   // per-wave P, padded stride 144B, 18KB
  const int lin = blockIdx.x;           // 0..511
  const int swz = (lin & 7) * 64 + (lin >> 3);
  const int qpair = swz & 7;            // 0..7
  const int bh = swz >> 3;              // 0..63
  const int tid = threadIdx.x, w = tid >> 6, lane = tid & 63;
  const int l16 = lane & 15, l4 = lane >> 4;
  const int b = bh >> 4, h = bh & 15;

  const u16* kbase = k_r + (size_t)bh * Tt * HDn;
  const u16* vbase = vt + (size_t)bh * HDn * Tt;
  const f32x4 zf = {0.f, 0.f, 0.f, 0.f};

  auto stageK = [&](int buf, int j) {
    const char* ksrc = (const char*)(kbase + (size_t)j * 64 * HDn);
#pragma unroll
    for (int i = 0; i < 4; i++) {
      int op = tid * 16 + i * 4096;
      int ol = op ^ (((op >> 8) & 7) << 4);   // K rows are 256B
      gl_lds16(ksrc + ol, (char*)&Ks[buf][0] + op);
    }
  };
  auto stageV = [&](int j) {
    const char* vsrc = (const char*)(vbase + (size_t)j * 64);
#pragma unroll
    for (int i = 0; i < 4; i++) {
      int op = tid * 16 + i * 4096;
      int ol = op ^ (((op >> 7) & 7) << 4);   // V^T rows are 128B
      int row = ol >> 7, colb = ol & 127;
      gl_lds16(vsrc + (size_t)row * (Tt * 2) + colb, (char*)Vs + op);
    }
  };

#pragma unroll
  for (int qsel = 0; qsel < 2; ++qsel) {
    const int qt = qsel ? (15 - qpair) : qpair;

    const u16* qbase = q_r + ((size_t)bh * Tt + qt * 128 + w * 32) * HDn;
    bf16x8 qf[2][4];
#pragma unroll
    for (int mi = 0; mi < 2; mi++)
#pragma unroll
      for (int kc = 0; kc < 4; kc++)
        qf[mi][kc] = *(const bf16x8*)(qbase + (size_t)(mi * 16 + l16) * HDn + kc * 32 + l4 * 8);

    f32x4 acc_o[2][8];
#pragma unroll
    for (int mi = 0; mi < 2; mi++)
#pragma unroll
      for (int nf = 0; nf < 8; nf++) acc_o[mi][nf] = zf;
    float mrow[2][4], lrow[2][4];
#pragma unroll
    for (int mi = 0; mi < 2; mi++)
#pragma unroll
      for (int jj = 0; jj < 4; jj++) { mrow[mi][jj] = -1e30f; lrow[mi][jj] = 0.f; }

    const int ntiles = 2 * qt + 2;
    stageK(0, 0);
    __syncthreads();                 // K(0) landed + visible
    int cur = 0;

    for (int j = 0; j < ntiles; ++j) {
      const bool more = (j + 1 < ntiles);
      stageV(j);                     // 4 loads, consumed after mid barrier
      if (more) stageK(cur ^ 1, j + 1);  // 4 loads, consumed next iteration

      // ---- S = Q K^T from Ks[cur] ----
      f32x4 s[2][4];
#pragma unroll
      for (int mi = 0; mi < 2; mi++)
#pragma unroll
        for (int nj = 0; nj < 4; nj++) s[mi][nj] = zf;
#pragma unroll
      for (int kc = 0; kc < 4; kc++) {
        bf16x8 kf[4];
#pragma unroll
        for (int nj = 0; nj < 4; nj++) {
          int row = nj * 16 + l16;
          kf[nj] = *(const bf16x8*)((const char*)&Ks[cur][0] + row * 256 +
                                    ((kc * 64 + l4 * 16) ^ ((row & 7) << 4)));
        }
        __builtin_amdgcn_s_setprio(1);
#pragma unroll
        for (int mi = 0; mi < 2; mi++)
#pragma unroll
          for (int nj = 0; nj < 4; nj++)
            s[mi][nj] = __builtin_amdgcn_mfma_f32_16x16x32_bf16(qf[mi][kc], kf[nj], s[mi][nj], 0, 0, 0);
        __builtin_amdgcn_s_setprio(0);
      }

      // ---- online softmax (wave-parallel; rescale only when max grows) ----
      const bool diag = (j >= 2 * qt);
#pragma unroll
      for (int mi = 0; mi < 2; mi++) {
#pragma unroll
        for (int jj = 0; jj < 4; jj++) {
          if (diag) {
            const int qrow = qt * 128 + w * 32 + mi * 16 + l4 * 4 + jj;
#pragma unroll
            for (int nj = 0; nj < 4; nj++) {
              const int key = j * 64 + nj * 16 + l16;
              if (key > qrow) s[mi][nj][jj] = -1e30f;
            }
          }
          float lm = fmaxf(fmaxf(s[mi][0][jj], s[mi][1][jj]), fmaxf(s[mi][2][jj], s[mi][3][jj]));
#pragma unroll
          for (int dd = 1; dd < 16; dd <<= 1) lm = fmaxf(lm, __shfl_xor(lm, dd));
          if (lm > mrow[mi][jj]) {
            const float sc = __expf(mrow[mi][jj] - lm);
            mrow[mi][jj] = lm;
            lrow[mi][jj] *= sc;
#pragma unroll
            for (int nf = 0; nf < 8; nf++) acc_o[mi][nf][jj] *= sc;
          }
          float ps = 0.f;
#pragma unroll
          for (int nj = 0; nj < 4; nj++) {
            float p = __expf(s[mi][nj][jj] - mrow[mi][jj]);
            s[mi][nj][jj] = p;
            ps += p;
          }
#pragma unroll
          for (int dd = 1; dd < 16; dd <<= 1) ps += __shfl_xor(ps, dd);
          lrow[mi][jj] += ps;
          const int prow = mi * 16 + l4 * 4 + jj;
#pragma unroll
          for (int nj = 0; nj < 4; nj++)
            Ps[w][prow * 72 + nj * 16 + l16] = f2bf(s[mi][nj][jj]);
        }
      }

      // ---- V(j) landed? (K(j+1)'s 4 loads may remain in flight) ----
      if (more) { WAITV(4); } else { WAITV(0); }
      __builtin_amdgcn_s_barrier();

      // ---- O += P V from Vs ----
#pragma unroll
      for (int kc = 0; kc < 2; kc++) {
        bf16x8 pf[2];
#pragma unroll
        for (int mi = 0; mi < 2; mi++)
          pf[mi] = *(const bf16x8*)((const char*)&Ps[w][0] + (mi * 16 + l16) * 144 + kc * 64 + l4 * 16);
        bf16x8 vf[8];
#pragma unroll
        for (int nf = 0; nf < 8; nf++) {
          int row = nf * 16 + l16;
          vf[nf] = *(const bf16x8*)((const char*)Vs + row * 128 +
                                    ((kc * 64 + l4 * 16) ^ ((row & 7) << 4)));
        }
        __builtin_amdgcn_s_setprio(1);
#pragma unroll
        for (int nf = 0; nf < 8; nf++)
#pragma unroll
          for (int mi = 0; mi < 2; mi++)
            acc_o[mi][nf] = __builtin_amdgcn_mfma_f32_16x16x32_bf16(pf[mi], vf[nf], acc_o[mi][nf], 0, 0, 0);
        __builtin_amdgcn_s_setprio(0);
      }
      __syncthreads();               // drains vmcnt(0): K(j+1) landed; reads done
      cur ^= 1;
    }

    // ---- epilogue for this q-tile ----
#pragma unroll
    for (int mi = 0; mi < 2; mi++) {
#pragma unroll
      for (int jj = 0; jj < 4; jj++) {
        const float rinv = 1.f / lrow[mi][jj];
        const int t = qt * 128 + w * 32 + mi * 16 + l4 * 4 + jj;
        u16* yrow = y + ((size_t)b * Tt + t) * Ccn + h * HDn;
#pragma unroll
        for (int nf = 0; nf < 8; nf++)
          yrow[nf * 16 + l16] = f2bf(acc_o[mi][nf][jj] * rinv);
      }
    }
    __syncthreads();                 // all epilogue reads done before next qsel stages
  }
}

// ---------------- launcher ----------------

extern "C" void kernel_launch(void* const* d_in, const int* in_sizes, int n_in,
                              void* d_out, int out_size, void* d_ws, size_t ws_size,
                              hipStream_t stream) {
  const float* x     = (const float*)d_in[0];
  const float* Wqkv  = (const float*)d_in[1];
  const float* bqkv  = (const float*)d_in[2];
  const float* Wproj = (const float*)d_in[3];
  const float* bproj = (const float*)d_in[4];
  float* out = (float*)d_out;
  char* ws = (char*)d_ws;

  size_t off = 0;
  auto alloc = [&](size_t bytes) -> char* {
    char* p = ws + off;
    off += (bytes + 255) & ~(size_t)255;
    return p;
  };
  float* ctab  = (float*)alloc((size_t)Tt * 64 * sizeof(float));
  float* stab  = (float*)alloc((size_t)Tt * 64 * sizeof(float));
  u16* xb      = (u16*)alloc((size_t)MM * Ccn * 2);
  u16* WqkvT   = (u16*)alloc((size_t)NQKV * Ccn * 2);
  u16* WprojT  = (u16*)alloc((size_t)Ccn * Ccn * 2);
  u16* q_rb    = (u16*)alloc((size_t)MM * Ccn * 2);
  u16* k_rb    = (u16*)alloc((size_t)MM * Ccn * 2);
  u16* v_rb    = (u16*)alloc((size_t)MM * Ccn * 2);
  u16* ybuf    = (u16*)alloc((size_t)MM * Ccn * 2);
  u16* vtb     = xb;  // alias: xb dead after GEMM1

  k_rope_table<<<(Tt * 64 + 255) / 256, 256, 0, stream>>>(ctab, stab);
  k_cvt<<<1024, 256, 0, stream>>>(x, xb, MM * Ccn);
  k_transpose_cvt<<<dim3(NQKV / 64, Ccn / 64), 256, 0, stream>>>(Wqkv, WqkvT, Ccn, NQKV);
  k_transpose_cvt<<<dim3(Ccn / 64, Ccn / 64), 256, 0, stream>>>(Wproj, WprojT, Ccn, Ccn);

  k_gemm256<0><<<dim3((MM / 256) * (NQKV / 256)), 512, 0, stream>>>(
      xb, WqkvT, NQKV, Ccn, NQKV / 256, bqkv, q_rb, k_rb, v_rb, ctab, stab, nullptr);

  k_vtrans<<<dim3(Tt / 64, HDn / 64, Bb * NHn), 256, 0, stream>>>(v_rb, vtb);

  k_attn<<<dim3(512), 256, 0, stream>>>(q_rb, k_rb, vtb, ybuf);

  k_gemm256<1><<<dim3((MM / 256) * (Ccn / 256)), 512, 0, stream>>>(
      ybuf, WprojT, Ccn, Ccn, Ccn / 256, bproj, nullptr, nullptr, nullptr, nullptr, nullptr, out);
}

// Round 6
// 524.790 us; speedup vs baseline: 1.0850x; 1.0850x over previous
//
#include <hip/hip_runtime.h>
#include <hip/hip_bf16.h>
#include <stdint.h>

#define DEV __device__ __forceinline__
#define WAITV(n) asm volatile("s_waitcnt vmcnt(" #n ")" ::: "memory")
#define WAITLGKM0 asm volatile("s_waitcnt lgkmcnt(0)" ::: "memory")
#define SCHEDB __builtin_amdgcn_sched_barrier(0)

typedef __attribute__((ext_vector_type(4))) float f32x4;
typedef __attribute__((ext_vector_type(8))) short bf16x8;
typedef unsigned short u16;

constexpr int Bb = 4, Tt = 2048, Ccn = 2048, NHn = 16, HDn = 128;
constexpr int MM = Bb * Tt;          // 8192
constexpr int NQKV = 3 * Ccn;        // 6144
constexpr int KD = 2048;             // K dim for BOTH GEMMs (constexpr!)
constexpr size_t K2 = (size_t)KD * 2;  // row stride bytes
constexpr float QSCALE = 0.08838834764831845f;  // 1/sqrt(128)

DEV u16 f2bf(float f) {
  __hip_bfloat16 h = __float2bfloat16(f);
  return *reinterpret_cast<u16*>(&h);
}

DEV void gl_lds16(const void* g, void* l) {
  __builtin_amdgcn_global_load_lds(
      (const __attribute__((address_space(1))) void*)g,
      (__attribute__((address_space(3))) void*)l, 16, 0, 0);
}

// ---------------- prep kernels ----------------

__global__ void k_rope_table(float* __restrict__ ct, float* __restrict__ st) {
  int idx = blockIdx.x * blockDim.x + threadIdx.x;
  if (idx >= Tt * 64) return;
  int t = idx >> 6, j = idx & 63;
  float invf = expf(-(float)j * 0.14391157f);  // ln(10000)/64
  float a = (float)t * invf;
  ct[idx] = cosf(a);
  st[idx] = sinf(a);
}

__global__ void k_cvt(const float* __restrict__ in, u16* __restrict__ out, int n) {
  int i = blockIdx.x * blockDim.x + threadIdx.x;
  int stride = gridDim.x * blockDim.x;
  int n4 = n >> 2;
  for (int idx = i; idx < n4; idx += stride) {
    float4 v = ((const float4*)in)[idx];
    ushort4 o;
    o.x = f2bf(v.x); o.y = f2bf(v.y); o.z = f2bf(v.z); o.w = f2bf(v.w);
    ((ushort4*)out)[idx] = o;
  }
}

// in: fp32 [R][NC]  ->  out: bf16 [NC][R]
__global__ void k_transpose_cvt(const float* __restrict__ in, u16* __restrict__ out,
                                int R, int NC) {
  __shared__ u16 tile[64][72];
  int tr = blockIdx.y * 64, tc = blockIdx.x * 64;
  int r = threadIdx.x >> 2, c = (threadIdx.x & 3) * 16;
  const float* src = in + (size_t)(tr + r) * NC + tc + c;
#pragma unroll
  for (int i = 0; i < 16; i++) tile[r][c + i] = f2bf(src[i]);
  __syncthreads();
  u16* dst = out + (size_t)(tc + r) * R + tr + c;
#pragma unroll
  for (int i = 0; i < 16; i++) dst[i] = tile[c + i][r];
}

// v [BH][T][D] -> vt [BH][D][T]
__global__ void k_vtrans(const u16* __restrict__ v, u16* __restrict__ vt) {
  __shared__ u16 tile[64][72];
  int bh = blockIdx.z;
  int t0 = blockIdx.x * 64, d0 = blockIdx.y * 64;
  int r = threadIdx.x >> 2, c = (threadIdx.x & 3) * 16;
  const u16* src = v + ((size_t)bh * Tt + t0) * HDn + d0;
#pragma unroll
  for (int i = 0; i < 16; i++) tile[r][c + i] = src[(size_t)r * HDn + c + i];
  __syncthreads();
  u16* dst = vt + ((size_t)bh * HDn + d0) * Tt + t0;
#pragma unroll
  for (int i = 0; i < 16; i++) dst[(size_t)r * Tt + c + i] = tile[c + i][r];
}

// ---------------- 256x256 8-phase GEMM (A [M][K] x Bt [N][K], bf16) ------
// 8 waves (2Mx4N), BK=64, 2 K-tiles/iter, 8 phases, counted vmcnt.
// Phase discipline per m201 template: {ds_reads; SCHEDB; stage; s_barrier;
// lgkmcnt(0); SCHEDB; setprio(1); 16 MFMA; setprio(0); s_barrier}.
// R5 relied on compiler lgkmcnt around raw s_barrier -> LLVM sinks ds_reads
// past the barrier into the MFMA cluster (s_barrier is not a sched fence),
// putting LDS latency on the critical path each phase (31% MfmaUtil).

template <int MODE>
__global__ __launch_bounds__(512, 2) void k_gemm256(
    const u16* __restrict__ A, const u16* __restrict__ Bt,
    int Ndim, int NBX,
    const float* __restrict__ bias,
    u16* __restrict__ q_r, u16* __restrict__ k_r, u16* __restrict__ v_r,
    const float* __restrict__ ctab, const float* __restrict__ stab,
    float* __restrict__ outp) {
  __shared__ u16 As[2][2][8192];   // [buf][half][128*64]
  __shared__ u16 Bs[2][2][8192];
  const int tid = threadIdx.x;
  const int w = tid >> 6, lane = tid & 63;
  const int l16 = lane & 15, l4 = lane >> 4;
  const int wr = w >> 2, wc = w & 3;
  const int bid = blockIdx.x, nwg = gridDim.x;
  const int swz = (bid & 7) * (nwg >> 3) + (bid >> 3);   // XCD-aware (R4)
  const int by = swz / NBX, bx = swz % NBX;
  const int m0 = by * 256, n0 = bx * 256;
  constexpr int NT = KD >> 6;      // 32
  constexpr int NIT = NT >> 1;     // 16

  // loop-invariant swizzled source offsets for the 2 loads of a half-tile
  size_t soff[2];
#pragma unroll
  for (int i = 0; i < 2; i++) {
    int op = i * 8192 + tid * 16;
    int ol = op ^ (((op >> 7) & 7) << 4);
    int row = ol >> 7, colb = ol & 127;
    soff[i] = (size_t)row * K2 + (size_t)colb;
  }
  const char* Abase = (const char*)A + (size_t)m0 * K2;
  const char* Bbase = (const char*)Bt + (size_t)n0 * K2;

  auto stA = [&](int buf, int half, int kt) {
#pragma unroll
    for (int i = 0; i < 2; i++)
      gl_lds16(Abase + (size_t)half * (128 * K2) + (size_t)kt * 128 + soff[i],
               (char*)&As[buf][half][0] + i * 8192 + tid * 16);
  };
  auto stB = [&](int buf, int half, int kt) {
#pragma unroll
    for (int i = 0; i < 2; i++)
      gl_lds16(Bbase + (size_t)half * (128 * K2) + (size_t)kt * 128 + soff[i],
               (char*)&Bs[buf][half][0] + i * 8192 + tid * 16);
  };
  auto rdA = [&](int buf, int mi, int ks) -> bf16x8 {
    int row = mi * 16 + l16;
    int kb = ks * 64 + l4 * 16;
    return *(const bf16x8*)((const char*)&As[buf][wr][0] + row * 128 + (kb ^ ((row & 7) << 4)));
  };
  auto rdB = [&](int buf, int nj, int ks) -> bf16x8 {
    int row = (wc & 1) * 64 + nj * 16 + l16;
    int kb = ks * 64 + l4 * 16;
    return *(const bf16x8*)((const char*)&Bs[buf][wc >> 1][0] + row * 128 + (kb ^ ((row & 7) << 4)));
  };

  f32x4 acc[8][4];
  const f32x4 zf = {0.f, 0.f, 0.f, 0.f};
#pragma unroll
  for (int i = 0; i < 8; i++)
#pragma unroll
    for (int j = 0; j < 4; j++) acc[i][j] = zf;

  // prologue: tile0 (A,B) + tile1 (B); tile1 A staged in iter0 ph0/ph1
  stA(0, 0, 0); stA(0, 1, 0); stB(0, 0, 0); stB(0, 1, 0);
  stB(1, 0, 1); stB(1, 1, 1);
  WAITV(4);                       // tile0 landed; tile1-B in flight
  __builtin_amdgcn_s_barrier();

  bf16x8 bfrag[4][2];
  for (int I = 0; I < NIT; ++I) {
    const int t1 = 2 * I + 1, t2 = 2 * I + 2, t3 = 2 * I + 3;
#pragma unroll
    for (int buf = 0; buf < 2; ++buf) {
#pragma unroll
      for (int ph = 0; ph < 4; ++ph) {
        const int gp = buf * 4 + ph;
        // ---- ds-reads for this phase (issued pre-barrier, pinned) ----
        if (ph == 0) {
#pragma unroll
          for (int nj = 0; nj < 4; nj++)
#pragma unroll
            for (int ks = 0; ks < 2; ks++) bfrag[nj][ks] = rdB(buf, nj, ks);
        }
        bf16x8 af[2][2];
#pragma unroll
        for (int dm = 0; dm < 2; dm++)
#pragma unroll
          for (int ks = 0; ks < 2; ks++) af[dm][ks] = rdA(buf, ph * 2 + dm, ks);
        SCHEDB;                      // pin reads before barrier
        // ---- stage one half-tile ----
        if (gp == 0)      stA(1, 0, t1);
        else if (gp == 1) stA(1, 1, t1);
        else if (gp == 2) { if (t2 < NT) stB(0, 0, t2); }
        else if (gp == 3) {
          if (t2 < NT) stB(0, 1, t2);
          if (I < NIT - 1) { WAITV(4); } else { WAITV(0); }
        }
        else if (gp == 4) { if (t2 < NT) stA(0, 0, t2); }
        else if (gp == 5) { if (t2 < NT) stA(0, 1, t2); }
        else if (gp == 6) { if (t3 < NT) stB(1, 0, t3); }
        else if (gp == 7) { if (t3 < NT) { stB(1, 1, t3); WAITV(4); } }
        __builtin_amdgcn_s_barrier();
        WAITLGKM0;                   // reads complete; coalesced wait
        SCHEDB;                      // no MFMA hoist above, no read sink below
        __builtin_amdgcn_s_setprio(1);
#pragma unroll
        for (int ks = 0; ks < 2; ks++)
#pragma unroll
          for (int dm = 0; dm < 2; dm++)
#pragma unroll
            for (int nj = 0; nj < 4; nj++)
              acc[ph * 2 + dm][nj] = __builtin_amdgcn_mfma_f32_16x16x32_bf16(
                  af[dm][ks], bfrag[nj][ks], acc[ph * 2 + dm][nj], 0, 0, 0);
        __builtin_amdgcn_s_setprio(0);
        __builtin_amdgcn_s_barrier();
      }
    }
  }

  if constexpr (MODE == 1) {
#pragma unroll
    for (int mi = 0; mi < 8; mi++) {
      const int mrow = m0 + wr * 128 + mi * 16 + l4 * 4;
#pragma unroll
      for (int nj = 0; nj < 4; nj++) {
        const int col = n0 + wc * 64 + nj * 16 + l16;
        const float bi = bias[col];
#pragma unroll
        for (int jj = 0; jj < 4; jj++)
          outp[(size_t)(mrow + jj) * Ndim + col] = acc[mi][nj][jj] + bi;
      }
    }
  } else {
#pragma unroll
    for (int mi = 0; mi < 8; mi++) {
      const int mrow = m0 + wr * 128 + mi * 16 + l4 * 4;
#pragma unroll
      for (int nj = 0; nj < 4; nj++) {
        const int n = n0 + wc * 64 + nj * 16 + l16;
        const float bi = bias[n];
        const int part = n >> 11;          // 0=q 1=k 2=v
        const int hcol = n & 2047;
        const int h = hcol >> 7, d = hcol & 127;
        const int dm = d & 63;
#pragma unroll
        for (int jj = 0; jj < 4; jj++) {
          const int m = mrow + jj;
          const int b = m >> 11, t = m & 2047;
          float val = acc[mi][nj][jj] + bi;
          size_t didx = (((size_t)b * NHn + h) * Tt + t) * HDn + d;
          if (part == 2) {
            v_r[didx] = f2bf(val);
          } else {
            float partner = __shfl_xor(val, 1);
            float rh = (d & 1) ? partner : -partner;
            float cs = ctab[t * 64 + dm], sn = stab[t * 64 + dm];
            float o = val * cs + rh * sn;
            if (part == 0) q_r[didx] = f2bf(o * QSCALE);
            else           k_r[didx] = f2bf(o);
          }
        }
      }
    }
  }
}

// ---------------- flash attention (causal), overlapped LDS staging -------
// (unchanged from R4: 541us config)
__global__ __launch_bounds__(256, 2) void k_attn(
    const u16* __restrict__ q_r, const u16* __restrict__ k_r,
    const u16* __restrict__ vt, u16* __restrict__ y) {
  __shared__ u16 Ks[2][64 * 128];  // [buf][key][d], swizzled, 32KB
  __shared__ u16 Vs[128 * 64];     // V^T [d][key], swizzled, 16KB
  __shared__ u16 Ps[4][32 * 72];   // per-wave P, padded stride 144B, 18KB
  const int lin = blockIdx.x;           // 0..511
  const int swz = (lin & 7) * 64 + (lin >> 3);
  const int qpair = swz & 7;            // 0..7
  const int bh = swz >> 3;              // 0..63
  const int tid = threadIdx.x, w = tid >> 6, lane = tid & 63;
  const int l16 = lane & 15, l4 = lane >> 4;
  const int b = bh >> 4, h = bh & 15;

  const u16* kbase = k_r + (size_t)bh * Tt * HDn;
  const u16* vbase = vt + (size_t)bh * HDn * Tt;
  const f32x4 zf = {0.f, 0.f, 0.f, 0.f};

  auto stageK = [&](int buf, int j) {
    const char* ksrc = (const char*)(kbase + (size_t)j * 64 * HDn);
#pragma unroll
    for (int i = 0; i < 4; i++) {
      int op = tid * 16 + i * 4096;
      int ol = op ^ (((op >> 8) & 7) << 4);   // K rows are 256B
      gl_lds16(ksrc + ol, (char*)&Ks[buf][0] + op);
    }
  };
  auto stageV = [&](int j) {
    const char* vsrc = (const char*)(vbase + (size_t)j * 64);
#pragma unroll
    for (int i = 0; i < 4; i++) {
      int op = tid * 16 + i * 4096;
      int ol = op ^ (((op >> 7) & 7) << 4);   // V^T rows are 128B
      int row = ol >> 7, colb = ol & 127;
      gl_lds16(vsrc + (size_t)row * (Tt * 2) + colb, (char*)Vs + op);
    }
  };

#pragma unroll
  for (int qsel = 0; qsel < 2; ++qsel) {
    const int qt = qsel ? (15 - qpair) : qpair;

    const u16* qbase = q_r + ((size_t)bh * Tt + qt * 128 + w * 32) * HDn;
    bf16x8 qf[2][4];
#pragma unroll
    for (int mi = 0; mi < 2; mi++)
#pragma unroll
      for (int kc = 0; kc < 4; kc++)
        qf[mi][kc] = *(const bf16x8*)(qbase + (size_t)(mi * 16 + l16) * HDn + kc * 32 + l4 * 8);

    f32x4 acc_o[2][8];
#pragma unroll
    for (int mi = 0; mi < 2; mi++)
#pragma unroll
      for (int nf = 0; nf < 8; nf++) acc_o[mi][nf] = zf;
    float mrow[2][4], lrow[2][4];
#pragma unroll
    for (int mi = 0; mi < 2; mi++)
#pragma unroll
      for (int jj = 0; jj < 4; jj++) { mrow[mi][jj] = -1e30f; lrow[mi][jj] = 0.f; }

    const int ntiles = 2 * qt + 2;
    stageK(0, 0);
    __syncthreads();                 // K(0) landed + visible
    int cur = 0;

    for (int j = 0; j < ntiles; ++j) {
      const bool more = (j + 1 < ntiles);
      stageV(j);                     // 4 loads, consumed after mid barrier
      if (more) stageK(cur ^ 1, j + 1);  // 4 loads, consumed next iteration

      // ---- S = Q K^T from Ks[cur] ----
      f32x4 s[2][4];
#pragma unroll
      for (int mi = 0; mi < 2; mi++)
#pragma unroll
        for (int nj = 0; nj < 4; nj++) s[mi][nj] = zf;
#pragma unroll
      for (int kc = 0; kc < 4; kc++) {
        bf16x8 kf[4];
#pragma unroll
        for (int nj = 0; nj < 4; nj++) {
          int row = nj * 16 + l16;
          kf[nj] = *(const bf16x8*)((const char*)&Ks[cur][0] + row * 256 +
                                    ((kc * 64 + l4 * 16) ^ ((row & 7) << 4)));
        }
        __builtin_amdgcn_s_setprio(1);
#pragma unroll
        for (int mi = 0; mi < 2; mi++)
#pragma unroll
          for (int nj = 0; nj < 4; nj++)
            s[mi][nj] = __builtin_amdgcn_mfma_f32_16x16x32_bf16(qf[mi][kc], kf[nj], s[mi][nj], 0, 0, 0);
        __builtin_amdgcn_s_setprio(0);
      }

      // ---- online softmax (wave-parallel; rescale only when max grows) ----
      const bool diag = (j >= 2 * qt);
#pragma unroll
      for (int mi = 0; mi < 2; mi++) {
#pragma unroll
        for (int jj = 0; jj < 4; jj++) {
          if (diag) {
            const int qrow = qt * 128 + w * 32 + mi * 16 + l4 * 4 + jj;
#pragma unroll
            for (int nj = 0; nj < 4; nj++) {
              const int key = j * 64 + nj * 16 + l16;
              if (key > qrow) s[mi][nj][jj] = -1e30f;
            }
          }
          float lm = fmaxf(fmaxf(s[mi][0][jj], s[mi][1][jj]), fmaxf(s[mi][2][jj], s[mi][3][jj]));
#pragma unroll
          for (int dd = 1; dd < 16; dd <<= 1) lm = fmaxf(lm, __shfl_xor(lm, dd));
          if (lm > mrow[mi][jj]) {
            const float sc = __expf(mrow[mi][jj] - lm);
            mrow[mi][jj] = lm;
            lrow[mi][jj] *= sc;
#pragma unroll
            for (int nf = 0; nf < 8; nf++) acc_o[mi][nf][jj] *= sc;
          }
          float ps = 0.f;
#pragma unroll
          for (int nj = 0; nj < 4; nj++) {
            float p = __expf(s[mi][nj][jj] - mrow[mi][jj]);
            s[mi][nj][jj] = p;
            ps += p;
          }
#pragma unroll
          for (int dd = 1; dd < 16; dd <<= 1) ps += __shfl_xor(ps, dd);
          lrow[mi][jj] += ps;
          const int prow = mi * 16 + l4 * 4 + jj;
#pragma unroll
          for (int nj = 0; nj < 4; nj++)
            Ps[w][prow * 72 + nj * 16 + l16] = f2bf(s[mi][nj][jj]);
        }
      }

      // ---- V(j) landed? (K(j+1)'s 4 loads may remain in flight) ----
      if (more) { WAITV(4); } else { WAITV(0); }
      __builtin_amdgcn_s_barrier();

      // ---- O += P V from Vs ----
#pragma unroll
      for (int kc = 0; kc < 2; kc++) {
        bf16x8 pf[2];
#pragma unroll
        for (int mi = 0; mi < 2; mi++)
          pf[mi] = *(const bf16x8*)((const char*)&Ps[w][0] + (mi * 16 + l16) * 144 + kc * 64 + l4 * 16);
        bf16x8 vf[8];
#pragma unroll
        for (int nf = 0; nf < 8; nf++) {
          int row = nf * 16 + l16;
          vf[nf] = *(const bf16x8*)((const char*)Vs + row * 128 +
                                    ((kc * 64 + l4 * 16) ^ ((row & 7) << 4)));
        }
        __builtin_amdgcn_s_setprio(1);
#pragma unroll
        for (int nf = 0; nf < 8; nf++)
#pragma unroll
          for (int mi = 0; mi < 2; mi++)
            acc_o[mi][nf] = __builtin_amdgcn_mfma_f32_16x16x32_bf16(pf[mi], vf[nf], acc_o[mi][nf], 0, 0, 0);
        __builtin_amdgcn_s_setprio(0);
      }
      __syncthreads();               // drains vmcnt(0): K(j+1) landed; reads done
      cur ^= 1;
    }

    // ---- epilogue for this q-tile ----
#pragma unroll
    for (int mi = 0; mi < 2; mi++) {
#pragma unroll
      for (int jj = 0; jj < 4; jj++) {
        const float rinv = 1.f / lrow[mi][jj];
        const int t = qt * 128 + w * 32 + mi * 16 + l4 * 4 + jj;
        u16* yrow = y + ((size_t)b * Tt + t) * Ccn + h * HDn;
#pragma unroll
        for (int nf = 0; nf < 8; nf++)
          yrow[nf * 16 + l16] = f2bf(acc_o[mi][nf][jj] * rinv);
      }
    }
    __syncthreads();                 // all epilogue reads done before next qsel stages
  }
}

// ---------------- launcher ----------------

extern "C" void kernel_launch(void* const* d_in, const int* in_sizes, int n_in,
                              void* d_out, int out_size, void* d_ws, size_t ws_size,
                              hipStream_t stream) {
  const float* x     = (const float*)d_in[0];
  const float* Wqkv  = (const float*)d_in[1];
  const float* bqkv  = (const float*)d_in[2];
  const float* Wproj = (const float*)d_in[3];
  const float* bproj = (const float*)d_in[4];
  float* out = (float*)d_out;
  char* ws = (char*)d_ws;

  size_t off = 0;
  auto alloc = [&](size_t bytes) -> char* {
    char* p = ws + off;
    off += (bytes + 255) & ~(size_t)255;
    return p;
  };
  float* ctab  = (float*)alloc((size_t)Tt * 64 * sizeof(float));
  float* stab  = (float*)alloc((size_t)Tt * 64 * sizeof(float));
  u16* xb      = (u16*)alloc((size_t)MM * Ccn * 2);
  u16* WqkvT   = (u16*)alloc((size_t)NQKV * Ccn * 2);
  u16* WprojT  = (u16*)alloc((size_t)Ccn * Ccn * 2);
  u16* q_rb    = (u16*)alloc((size_t)MM * Ccn * 2);
  u16* k_rb    = (u16*)alloc((size_t)MM * Ccn * 2);
  u16* v_rb    = (u16*)alloc((size_t)MM * Ccn * 2);
  u16* ybuf    = (u16*)alloc((size_t)MM * Ccn * 2);
  u16* vtb     = xb;  // alias: xb dead after GEMM1

  k_rope_table<<<(Tt * 64 + 255) / 256, 256, 0, stream>>>(ctab, stab);
  k_cvt<<<1024, 256, 0, stream>>>(x, xb, MM * Ccn);
  k_transpose_cvt<<<dim3(NQKV / 64, Ccn / 64), 256, 0, stream>>>(Wqkv, WqkvT, Ccn, NQKV);
  k_transpose_cvt<<<dim3(Ccn / 64, Ccn / 64), 256, 0, stream>>>(Wproj, WprojT, Ccn, Ccn);

  k_gemm256<0><<<dim3((MM / 256) * (NQKV / 256)), 512, 0, stream>>>(
      xb, WqkvT, NQKV, NQKV / 256, bqkv, q_rb, k_rb, v_rb, ctab, stab, nullptr);

  k_vtrans<<<dim3(Tt / 64, HDn / 64, Bb * NHn), 256, 0, stream>>>(v_rb, vtb);

  k_attn<<<dim3(512), 256, 0, stream>>>(q_rb, k_rb, vtb, ybuf);

  k_gemm256<1><<<dim3((MM / 256) * (Ccn / 256)), 512, 0, stream>>>(
      ybuf, WprojT, Ccn, Ccn / 256, bproj, nullptr, nullptr, nullptr, nullptr, nullptr, out);
}

// Round 7
// 516.645 us; speedup vs baseline: 1.1021x; 1.0158x over previous
//
#include <hip/hip_runtime.h>
#include <hip/hip_bf16.h>
#include <stdint.h>

#define DEV __device__ __forceinline__
#define WAITV(n) asm volatile("s_waitcnt vmcnt(" #n ")" ::: "memory")
#define WAITLGKM0 asm volatile("s_waitcnt lgkmcnt(0)" ::: "memory")
#define SCHEDB __builtin_amdgcn_sched_barrier(0)

typedef __attribute__((ext_vector_type(4))) float f32x4;
typedef __attribute__((ext_vector_type(8))) short bf16x8;
typedef unsigned short u16;

constexpr int Bb = 4, Tt = 2048, Ccn = 2048, NHn = 16, HDn = 128;
constexpr int MM = Bb * Tt;          // 8192
constexpr int NQKV = 3 * Ccn;        // 6144
constexpr int KD = 2048;             // K dim for BOTH GEMMs
constexpr size_t K2 = (size_t)KD * 2;  // row stride bytes
constexpr float QSCALE = 0.08838834764831845f;  // 1/sqrt(128)

DEV u16 f2bf(float f) {
  __hip_bfloat16 h = __float2bfloat16(f);
  return *reinterpret_cast<u16*>(&h);
}

DEV void gl_lds16(const void* g, void* l) {
  __builtin_amdgcn_global_load_lds(
      (const __attribute__((address_space(1))) void*)g,
      (__attribute__((address_space(3))) void*)l, 16, 0, 0);
}

// ---------------- prep kernels ----------------

__global__ void k_rope_table(float* __restrict__ ct, float* __restrict__ st) {
  int idx = blockIdx.x * blockDim.x + threadIdx.x;
  if (idx >= Tt * 64) return;
  int t = idx >> 6, j = idx & 63;
  float invf = expf(-(float)j * 0.14391157f);  // ln(10000)/64
  float a = (float)t * invf;
  ct[idx] = cosf(a);
  st[idx] = sinf(a);
}

__global__ void k_cvt(const float* __restrict__ in, u16* __restrict__ out, int n) {
  int i = blockIdx.x * blockDim.x + threadIdx.x;
  int stride = gridDim.x * blockDim.x;
  int n4 = n >> 2;
  for (int idx = i; idx < n4; idx += stride) {
    float4 v = ((const float4*)in)[idx];
    ushort4 o;
    o.x = f2bf(v.x); o.y = f2bf(v.y); o.z = f2bf(v.z); o.w = f2bf(v.w);
    ((ushort4*)out)[idx] = o;
  }
}

// in: fp32 [R][NC]  ->  out: bf16 [NC][R]
__global__ void k_transpose_cvt(const float* __restrict__ in, u16* __restrict__ out,
                                int R, int NC) {
  __shared__ u16 tile[64][72];
  int tr = blockIdx.y * 64, tc = blockIdx.x * 64;
  int r = threadIdx.x >> 2, c = (threadIdx.x & 3) * 16;
  const float* src = in + (size_t)(tr + r) * NC + tc + c;
#pragma unroll
  for (int i = 0; i < 16; i++) tile[r][c + i] = f2bf(src[i]);
  __syncthreads();
  u16* dst = out + (size_t)(tc + r) * R + tr + c;
#pragma unroll
  for (int i = 0; i < 16; i++) dst[i] = tile[c + i][r];
}

// v [BH][T][D] -> vt [BH][D][T]
__global__ void k_vtrans(const u16* __restrict__ v, u16* __restrict__ vt) {
  __shared__ u16 tile[64][72];
  int bh = blockIdx.z;
  int t0 = blockIdx.x * 64, d0 = blockIdx.y * 64;
  int r = threadIdx.x >> 2, c = (threadIdx.x & 3) * 16;
  const u16* src = v + ((size_t)bh * Tt + t0) * HDn + d0;
#pragma unroll
  for (int i = 0; i < 16; i++) tile[r][c + i] = src[(size_t)r * HDn + c + i];
  __syncthreads();
  u16* dst = vt + ((size_t)bh * HDn + d0) * Tt + t0;
#pragma unroll
  for (int i = 0; i < 16; i++) dst[(size_t)r * Tt + c + i] = tile[c + i][r];
}

// ---------------- 256x256 8-phase GEMM (A [M][K] x Bt [N][K], bf16) ------
// 8 waves (2Mx4N), BK=64, 2 K-tiles/iter, 8 phases, counted vmcnt.
// R6 diagnosis: VALUBusy 19% = per-phase ADDRESS RECOMPUTATION on the
// critical path. Fix: algebraic split of the XOR-swizzled address into
// lane-constant base + compile-time immediate:
//   addr = mi*2048 + l16*128 + ((ks*64|l4*16) ^ ((l16&7)<<4))
//        = [l16*128 + ((l4*16)^(M&48)) + b6(ks)] + mi*2048 (+buf*32768)
// with M=(l16&7)<<4, b6(0)=M&64, b6(1)=64-(M&64)  (disjoint bit fields).
// -> 4 base pointers; every ds_read is base+imm. Zero VALU per read.
// LDS layout: one block; A at byte 0 (A[buf][half]), B at byte 65536.

template <int MODE>
__global__ __launch_bounds__(512, 2) void k_gemm256(
    const u16* __restrict__ A, const u16* __restrict__ Bt,
    int Ndim, int NBX,
    const float* __restrict__ bias,
    u16* __restrict__ q_r, u16* __restrict__ k_r, u16* __restrict__ v_r,
    const float* __restrict__ ctab, const float* __restrict__ stab,
    float* __restrict__ outp) {
  __shared__ __align__(16) u16 SM[65536];   // 128KB: A 64KB | B 64KB
  const int tid = threadIdx.x;
  const int w = tid >> 6, lane = tid & 63;
  const int l16 = lane & 15, l4 = lane >> 4;
  const int wr = w >> 2, wc = w & 3;
  const int bid = blockIdx.x, nwg = gridDim.x;
  const int swz = (bid & 7) * (nwg >> 3) + (bid >> 3);   // XCD-aware
  const int by = swz / NBX, bx = swz % NBX;
  const int m0 = by * 256, n0 = bx * 256;
  constexpr int NT = KD >> 6;      // 32
  constexpr int NIT = NT >> 1;     // 16

  // ---- precomputed LDS read bases (lane-constant) ----
  const int Mx = (l16 & 7) << 4;                    // XOR mask, bits 4-6
  const int b6 = Mx & 64;
  const int lane_lo = l16 * 128 + ((l4 * 16) ^ (Mx & 48));
  const char* const pA0 = (const char*)SM + wr * 16384 + lane_lo + b6;
  const char* const pA1 = (const char*)SM + wr * 16384 + lane_lo + (64 - b6);
  const char* const pB0 = (const char*)SM + 65536 + (wc >> 1) * 16384 + (wc & 1) * 8192 + lane_lo + b6;
  const char* const pB1 = (const char*)SM + 65536 + (wc >> 1) * 16384 + (wc & 1) * 8192 + lane_lo + (64 - b6);

  // ---- precomputed staging source pointers (lane-constant) ----
  size_t soff[2];
#pragma unroll
  for (int i = 0; i < 2; i++) {
    int op = i * 8192 + tid * 16;
    int ol = op ^ (((op >> 7) & 7) << 4);
    int row = ol >> 7, colb = ol & 127;
    soff[i] = (size_t)row * K2 + (size_t)colb;
  }
  const char* srcA[2][2];  // [half][i]
  const char* srcB[2][2];
#pragma unroll
  for (int hh = 0; hh < 2; hh++)
#pragma unroll
    for (int i = 0; i < 2; i++) {
      srcA[hh][i] = (const char*)A + (size_t)(m0 + hh * 128) * K2 + soff[i];
      srcB[hh][i] = (const char*)Bt + (size_t)(n0 + hh * 128) * K2 + soff[i];
    }
  char* const dstBase = (char*)SM;

  auto stA = [&](int buf, int half, int kt) {
#pragma unroll
    for (int i = 0; i < 2; i++)
      gl_lds16(srcA[half][i] + (size_t)kt * 128,
               dstBase + buf * 32768 + half * 16384 + i * 8192 + tid * 16);
  };
  auto stB = [&](int buf, int half, int kt) {
#pragma unroll
    for (int i = 0; i < 2; i++)
      gl_lds16(srcB[half][i] + (size_t)kt * 128,
               dstBase + 65536 + buf * 32768 + half * 16384 + i * 8192 + tid * 16);
  };

  f32x4 acc[8][4];
  const f32x4 zf = {0.f, 0.f, 0.f, 0.f};
#pragma unroll
  for (int i = 0; i < 8; i++)
#pragma unroll
    for (int j = 0; j < 4; j++) acc[i][j] = zf;

  // prologue: tile0 (A,B) + tile1 (B); tile1 A staged in iter0 ph0/ph1
  stA(0, 0, 0); stA(0, 1, 0); stB(0, 0, 0); stB(0, 1, 0);
  stB(1, 0, 1); stB(1, 1, 1);
  WAITV(4);                       // tile0 landed; tile1-B in flight
  __builtin_amdgcn_s_barrier();

  bf16x8 bfrag[4][2];
  for (int I = 0; I < NIT; ++I) {
    const int t1 = 2 * I + 1, t2 = 2 * I + 2, t3 = 2 * I + 3;
#pragma unroll
    for (int buf = 0; buf < 2; ++buf) {
#pragma unroll
      for (int ph = 0; ph < 4; ++ph) {
        const int gp = buf * 4 + ph;
        // ---- ds-reads for this phase: base + compile-time offset ----
        if (ph == 0) {
#pragma unroll
          for (int nj = 0; nj < 4; nj++) {
            bfrag[nj][0] = *(const bf16x8*)(pB0 + buf * 32768 + nj * 2048);
            bfrag[nj][1] = *(const bf16x8*)(pB1 + buf * 32768 + nj * 2048);
          }
        }
        bf16x8 af[2][2];
#pragma unroll
        for (int dm = 0; dm < 2; dm++) {
          af[dm][0] = *(const bf16x8*)(pA0 + buf * 32768 + (ph * 2 + dm) * 2048);
          af[dm][1] = *(const bf16x8*)(pA1 + buf * 32768 + (ph * 2 + dm) * 2048);
        }
        SCHEDB;                      // pin reads before barrier
        // ---- stage one half-tile ----
        if (gp == 0)      stA(1, 0, t1);
        else if (gp == 1) stA(1, 1, t1);
        else if (gp == 2) { if (t2 < NT) stB(0, 0, t2); }
        else if (gp == 3) {
          if (t2 < NT) stB(0, 1, t2);
          if (I < NIT - 1) { WAITV(4); } else { WAITV(0); }
        }
        else if (gp == 4) { if (t2 < NT) stA(0, 0, t2); }
        else if (gp == 5) { if (t2 < NT) stA(0, 1, t2); }
        else if (gp == 6) { if (t3 < NT) stB(1, 0, t3); }
        else if (gp == 7) { if (t3 < NT) { stB(1, 1, t3); WAITV(4); } }
        __builtin_amdgcn_s_barrier();
        WAITLGKM0;                   // all reads complete
        SCHEDB;                      // no MFMA hoist above, no read sink below
        __builtin_amdgcn_s_setprio(1);
#pragma unroll
        for (int ks = 0; ks < 2; ks++)
#pragma unroll
          for (int dm = 0; dm < 2; dm++)
#pragma unroll
            for (int nj = 0; nj < 4; nj++)
              acc[ph * 2 + dm][nj] = __builtin_amdgcn_mfma_f32_16x16x32_bf16(
                  af[dm][ks], bfrag[nj][ks], acc[ph * 2 + dm][nj], 0, 0, 0);
        __builtin_amdgcn_s_setprio(0);
        __builtin_amdgcn_s_barrier();
      }
    }
  }

  if constexpr (MODE == 1) {
#pragma unroll
    for (int mi = 0; mi < 8; mi++) {
      const int mrow = m0 + wr * 128 + mi * 16 + l4 * 4;
#pragma unroll
      for (int nj = 0; nj < 4; nj++) {
        const int col = n0 + wc * 64 + nj * 16 + l16;
        const float bi = bias[col];
#pragma unroll
        for (int jj = 0; jj < 4; jj++)
          outp[(size_t)(mrow + jj) * Ndim + col] = acc[mi][nj][jj] + bi;
      }
    }
  } else {
#pragma unroll
    for (int mi = 0; mi < 8; mi++) {
      const int mrow = m0 + wr * 128 + mi * 16 + l4 * 4;
#pragma unroll
      for (int nj = 0; nj < 4; nj++) {
        const int n = n0 + wc * 64 + nj * 16 + l16;
        const float bi = bias[n];
        const int part = n >> 11;          // 0=q 1=k 2=v
        const int hcol = n & 2047;
        const int h = hcol >> 7, d = hcol & 127;
        const int dm = d & 63;
#pragma unroll
        for (int jj = 0; jj < 4; jj++) {
          const int m = mrow + jj;
          const int b = m >> 11, t = m & 2047;
          float val = acc[mi][nj][jj] + bi;
          size_t didx = (((size_t)b * NHn + h) * Tt + t) * HDn + d;
          if (part == 2) {
            v_r[didx] = f2bf(val);
          } else {
            float partner = __shfl_xor(val, 1);
            float rh = (d & 1) ? partner : -partner;
            float cs = ctab[t * 64 + dm], sn = stab[t * 64 + dm];
            float o = val * cs + rh * sn;
            if (part == 0) q_r[didx] = f2bf(o * QSCALE);
            else           k_r[didx] = f2bf(o);
          }
        }
      }
    }
  }
}

// ---------------- flash attention (causal), overlapped LDS staging -------
// (unchanged from R4/R6 config)
__global__ __launch_bounds__(256, 2) void k_attn(
    const u16* __restrict__ q_r, const u16* __restrict__ k_r,
    const u16* __restrict__ vt, u16* __restrict__ y) {
  __shared__ u16 Ks[2][64 * 128];  // [buf][key][d], swizzled, 32KB
  __shared__ u16 Vs[128 * 64];     // V^T [d][key], swizzled, 16KB
  __shared__ u16 Ps[4][32 * 72];   // per-wave P, padded stride 144B, 18KB
  const int lin = blockIdx.x;           // 0..511
  const int swz = (lin & 7) * 64 + (lin >> 3);
  const int qpair = swz & 7;            // 0..7
  const int bh = swz >> 3;              // 0..63
  const int tid = threadIdx.x, w = tid >> 6, lane = tid & 63;
  const int l16 = lane & 15, l4 = lane >> 4;
  const int b = bh >> 4, h = bh & 15;

  const u16* kbase = k_r + (size_t)bh * Tt * HDn;
  const u16* vbase = vt + (size_t)bh * HDn * Tt;
  const f32x4 zf = {0.f, 0.f, 0.f, 0.f};

  auto stageK = [&](int buf, int j) {
    const char* ksrc = (const char*)(kbase + (size_t)j * 64 * HDn);
#pragma unroll
    for (int i = 0; i < 4; i++) {
      int op = tid * 16 + i * 4096;
      int ol = op ^ (((op >> 8) & 7) << 4);   // K rows are 256B
      gl_lds16(ksrc + ol, (char*)&Ks[buf][0] + op);
    }
  };
  auto stageV = [&](int j) {
    const char* vsrc = (const char*)(vbase + (size_t)j * 64);
#pragma unroll
    for (int i = 0; i < 4; i++) {
      int op = tid * 16 + i * 4096;
      int ol = op ^ (((op >> 7) & 7) << 4);   // V^T rows are 128B
      int row = ol >> 7, colb = ol & 127;
      gl_lds16(vsrc + (size_t)row * (Tt * 2) + colb, (char*)Vs + op);
    }
  };

#pragma unroll
  for (int qsel = 0; qsel < 2; ++qsel) {
    const int qt = qsel ? (15 - qpair) : qpair;

    const u16* qbase = q_r + ((size_t)bh * Tt + qt * 128 + w * 32) * HDn;
    bf16x8 qf[2][4];
#pragma unroll
    for (int mi = 0; mi < 2; mi++)
#pragma unroll
      for (int kc = 0; kc < 4; kc++)
        qf[mi][kc] = *(const bf16x8*)(qbase + (size_t)(mi * 16 + l16) * HDn + kc * 32 + l4 * 8);

    f32x4 acc_o[2][8];
#pragma unroll
    for (int mi = 0; mi < 2; mi++)
#pragma unroll
      for (int nf = 0; nf < 8; nf++) acc_o[mi][nf] = zf;
    float mrow[2][4], lrow[2][4];
#pragma unroll
    for (int mi = 0; mi < 2; mi++)
#pragma unroll
      for (int jj = 0; jj < 4; jj++) { mrow[mi][jj] = -1e30f; lrow[mi][jj] = 0.f; }

    const int ntiles = 2 * qt + 2;
    stageK(0, 0);
    __syncthreads();                 // K(0) landed + visible
    int cur = 0;

    for (int j = 0; j < ntiles; ++j) {
      const bool more = (j + 1 < ntiles);
      stageV(j);                     // 4 loads, consumed after mid barrier
      if (more) stageK(cur ^ 1, j + 1);  // 4 loads, consumed next iteration

      // ---- S = Q K^T from Ks[cur] ----
      f32x4 s[2][4];
#pragma unroll
      for (int mi = 0; mi < 2; mi++)
#pragma unroll
        for (int nj = 0; nj < 4; nj++) s[mi][nj] = zf;
#pragma unroll
      for (int kc = 0; kc < 4; kc++) {
        bf16x8 kf[4];
#pragma unroll
        for (int nj = 0; nj < 4; nj++) {
          int row = nj * 16 + l16;
          kf[nj] = *(const bf16x8*)((const char*)&Ks[cur][0] + row * 256 +
                                    ((kc * 64 + l4 * 16) ^ ((row & 7) << 4)));
        }
        __builtin_amdgcn_s_setprio(1);
#pragma unroll
        for (int mi = 0; mi < 2; mi++)
#pragma unroll
          for (int nj = 0; nj < 4; nj++)
            s[mi][nj] = __builtin_amdgcn_mfma_f32_16x16x32_bf16(qf[mi][kc], kf[nj], s[mi][nj], 0, 0, 0);
        __builtin_amdgcn_s_setprio(0);
      }

      // ---- online softmax (wave-parallel; rescale only when max grows) ----
      const bool diag = (j >= 2 * qt);
#pragma unroll
      for (int mi = 0; mi < 2; mi++) {
#pragma unroll
        for (int jj = 0; jj < 4; jj++) {
          if (diag) {
            const int qrow = qt * 128 + w * 32 + mi * 16 + l4 * 4 + jj;
#pragma unroll
            for (int nj = 0; nj < 4; nj++) {
              const int key = j * 64 + nj * 16 + l16;
              if (key > qrow) s[mi][nj][jj] = -1e30f;
            }
          }
          float lm = fmaxf(fmaxf(s[mi][0][jj], s[mi][1][jj]), fmaxf(s[mi][2][jj], s[mi][3][jj]));
#pragma unroll
          for (int dd = 1; dd < 16; dd <<= 1) lm = fmaxf(lm, __shfl_xor(lm, dd));
          if (lm > mrow[mi][jj]) {
            const float sc = __expf(mrow[mi][jj] - lm);
            mrow[mi][jj] = lm;
            lrow[mi][jj] *= sc;
#pragma unroll
            for (int nf = 0; nf < 8; nf++) acc_o[mi][nf][jj] *= sc;
          }
          float ps = 0.f;
#pragma unroll
          for (int nj = 0; nj < 4; nj++) {
            float p = __expf(s[mi][nj][jj] - mrow[mi][jj]);
            s[mi][nj][jj] = p;
            ps += p;
          }
#pragma unroll
          for (int dd = 1; dd < 16; dd <<= 1) ps += __shfl_xor(ps, dd);
          lrow[mi][jj] += ps;
          const int prow = mi * 16 + l4 * 4 + jj;
#pragma unroll
          for (int nj = 0; nj < 4; nj++)
            Ps[w][prow * 72 + nj * 16 + l16] = f2bf(s[mi][nj][jj]);
        }
      }

      // ---- V(j) landed? (K(j+1)'s 4 loads may remain in flight) ----
      if (more) { WAITV(4); } else { WAITV(0); }
      __builtin_amdgcn_s_barrier();

      // ---- O += P V from Vs ----
#pragma unroll
      for (int kc = 0; kc < 2; kc++) {
        bf16x8 pf[2];
#pragma unroll
        for (int mi = 0; mi < 2; mi++)
          pf[mi] = *(const bf16x8*)((const char*)&Ps[w][0] + (mi * 16 + l16) * 144 + kc * 64 + l4 * 16);
        bf16x8 vf[8];
#pragma unroll
        for (int nf = 0; nf < 8; nf++) {
          int row = nf * 16 + l16;
          vf[nf] = *(const bf16x8*)((const char*)Vs + row * 128 +
                                    ((kc * 64 + l4 * 16) ^ ((row & 7) << 4)));
        }
        __builtin_amdgcn_s_setprio(1);
#pragma unroll
        for (int nf = 0; nf < 8; nf++)
#pragma unroll
          for (int mi = 0; mi < 2; mi++)
            acc_o[mi][nf] = __builtin_amdgcn_mfma_f32_16x16x32_bf16(pf[mi], vf[nf], acc_o[mi][nf], 0, 0, 0);
        __builtin_amdgcn_s_setprio(0);
      }
      __syncthreads();               // drains vmcnt(0): K(j+1) landed; reads done
      cur ^= 1;
    }

    // ---- epilogue for this q-tile ----
#pragma unroll
    for (int mi = 0; mi < 2; mi++) {
#pragma unroll
      for (int jj = 0; jj < 4; jj++) {
        const float rinv = 1.f / lrow[mi][jj];
        const int t = qt * 128 + w * 32 + mi * 16 + l4 * 4 + jj;
        u16* yrow = y + ((size_t)b * Tt + t) * Ccn + h * HDn;
#pragma unroll
        for (int nf = 0; nf < 8; nf++)
          yrow[nf * 16 + l16] = f2bf(acc_o[mi][nf][jj] * rinv);
      }
    }
    __syncthreads();                 // all epilogue reads done before next qsel stages
  }
}

// ---------------- launcher ----------------

extern "C" void kernel_launch(void* const* d_in, const int* in_sizes, int n_in,
                              void* d_out, int out_size, void* d_ws, size_t ws_size,
                              hipStream_t stream) {
  const float* x     = (const float*)d_in[0];
  const float* Wqkv  = (const float*)d_in[1];
  const float* bqkv  = (const float*)d_in[2];
  const float* Wproj = (const float*)d_in[3];
  const float* bproj = (const float*)d_in[4];
  float* out = (float*)d_out;
  char* ws = (char*)d_ws;

  size_t off = 0;
  auto alloc = [&](size_t bytes) -> char* {
    char* p = ws + off;
    off += (bytes + 255) & ~(size_t)255;
    return p;
  };
  float* ctab  = (float*)alloc((size_t)Tt * 64 * sizeof(float));
  float* stab  = (float*)alloc((size_t)Tt * 64 * sizeof(float));
  u16* xb      = (u16*)alloc((size_t)MM * Ccn * 2);
  u16* WqkvT   = (u16*)alloc((size_t)NQKV * Ccn * 2);
  u16* WprojT  = (u16*)alloc((size_t)Ccn * Ccn * 2);
  u16* q_rb    = (u16*)alloc((size_t)MM * Ccn * 2);
  u16* k_rb    = (u16*)alloc((size_t)MM * Ccn * 2);
  u16* v_rb    = (u16*)alloc((size_t)MM * Ccn * 2);
  u16* ybuf    = (u16*)alloc((size_t)MM * Ccn * 2);
  u16* vtb     = xb;  // alias: xb dead after GEMM1

  k_rope_table<<<(Tt * 64 + 255) / 256, 256, 0, stream>>>(ctab, stab);
  k_cvt<<<1024, 256, 0, stream>>>(x, xb, MM * Ccn);
  k_transpose_cvt<<<dim3(NQKV / 64, Ccn / 64), 256, 0, stream>>>(Wqkv, WqkvT, Ccn, NQKV);
  k_transpose_cvt<<<dim3(Ccn / 64, Ccn / 64), 256, 0, stream>>>(Wproj, WprojT, Ccn, Ccn);

  k_gemm256<0><<<dim3((MM / 256) * (NQKV / 256)), 512, 0, stream>>>(
      xb, WqkvT, NQKV, NQKV / 256, bqkv, q_rb, k_rb, v_rb, ctab, stab, nullptr);

  k_vtrans<<<dim3(Tt / 64, HDn / 64, Bb * NHn), 256, 0, stream>>>(v_rb, vtb);

  k_attn<<<dim3(512), 256, 0, stream>>>(q_rb, k_rb, vtb, ybuf);

  k_gemm256<1><<<dim3((MM / 256) * (Ccn / 256)), 512, 0, stream>>>(
      ybuf, WprojT, Ccn, Ccn / 256, bproj, nullptr, nullptr, nullptr, nullptr, nullptr, out);
}